// Round 1
// baseline (13164.861 us; speedup 1.0000x reference)
//
#include <hip/hip_runtime.h>

#define TSEQ 512
#define BATCH 64
#define INS 512
#define HID 1024
#define NOUT 128
#define NWG 256
#define NTHR 256

typedef _Float16 half8 __attribute__((ext_vector_type(8)));
typedef _Float16 half4v __attribute__((ext_vector_type(4)));
typedef float f32x4 __attribute__((ext_vector_type(4)));

__device__ __forceinline__ float sigf(float v) { return 1.0f / (1.0f + __expf(-v)); }

// Monotonic grid barrier: counter never resets (memset to 0 before launch).
// Relaxed spin (no per-poll cache invalidation), single agent-acquire fence on exit.
__device__ __forceinline__ void gbar(unsigned* cnt, unsigned tgt) {
  __syncthreads();  // drains vmcnt -> all this block's stores are at L2
  if (threadIdx.x == 0) {
    __hip_atomic_fetch_add(cnt, 1u, __ATOMIC_RELEASE, __HIP_MEMORY_SCOPE_AGENT);
    while (__hip_atomic_load(cnt, __ATOMIC_RELAXED, __HIP_MEMORY_SCOPE_AGENT) < tgt)
      __builtin_amdgcn_s_sleep(2);
  }
  __syncthreads();
  __builtin_amdgcn_fence(__ATOMIC_ACQUIRE, "agent");  // invalidate L1/L2 before reading remote h
}

__global__ __launch_bounds__(NTHR, 1) void lstm_persist(
    const float* __restrict__ x, const float* __restrict__ W_ih,
    const float* __restrict__ W_hh, const float* __restrict__ b_ih,
    const float* __restrict__ b_hh, const float* __restrict__ W_clf,
    const float* __restrict__ b_clf, float* __restrict__ out,
    void* ws, int use_xh) {
  // +8 f16 row padding: keeps 16B alignment for ds_read_b128, 2-way bank alias (free)
  __shared__ __align__(16) _Float16 Wih_s[16][INS + 8];
  __shared__ __align__(16) _Float16 Whh_s[16][HID + 8];
  __shared__ float gates_s[BATCH][16];
  __shared__ float bias_s[16];

  const int tid = threadIdx.x;
  const int wg = blockIdx.x;
  const int dim_base = wg << 2;  // this WG owns hidden dims [dim_base, dim_base+4)

  unsigned* cnt = (unsigned*)ws;
  _Float16* h0 = (_Float16*)((char*)ws + 256);
  _Float16* h1 = h0 + BATCH * HID;
  _Float16* xh = (_Float16*)((char*)ws + (512 << 10));

  // ---- stage weight slices to LDS (fp32 -> f16), col16 = gate*4 + local_dim ----
  for (int idx = tid; idx < 16 * INS; idx += NTHR) {
    int r = idx >> 9, k = idx & (INS - 1);
    int jg = ((r >> 2) << 10) + dim_base + (r & 3);
    Wih_s[r][k] = (_Float16)W_ih[jg * INS + k];
  }
  for (int idx = tid; idx < 16 * HID; idx += NTHR) {
    int r = idx >> 10, k = idx & (HID - 1);
    int jg = ((r >> 2) << 10) + dim_base + (r & 3);
    Whh_s[r][k] = (_Float16)W_hh[jg * HID + k];
  }
  if (tid < 16) {
    int jg = ((tid >> 2) << 10) + dim_base + (tid & 3);
    bias_s[tid] = b_ih[jg] + b_hh[jg];
  }
  __syncthreads();

  // ---- optional prologue: convert x to f16 once (grid-strided) ----
  if (use_xh) {
    const float4* xv = (const float4*)x;
    const int n4 = BATCH * TSEQ * INS / 4;
    for (int i = wg * NTHR + tid; i < n4; i += NWG * NTHR) {
      float4 v = xv[i];
      half4v hv = {(_Float16)v.x, (_Float16)v.y, (_Float16)v.z, (_Float16)v.w};
      *(half4v*)(xh + (size_t)i * 4) = hv;
    }
  }

  unsigned tgt = NWG;
  gbar(cnt, tgt); tgt += NWG;  // x-conversion visible (h0 zeroed by stream-ordered memset)

  // MFMA lane mapping (16x16x32): A[m=lane&15][k=quad*8+j], B[n=lane&15][k=quad*8+j],
  // D: col=lane&15, row=quad*4+reg   [verified layouts, m89/m91/m120]
  const int lane = tid & 63;
  const int wave = tid >> 6;
  const int m0 = wave << 4;        // 16-batch tile per wave
  const int nn = lane & 15;
  const int kq = (lane >> 4) << 3; // 0,8,16,24
  const int arow = m0 + nn;

  const int eb = tid >> 2;  // elementwise: batch  (matches wave's own MFMA rows)
  const int ed = tid & 3;   // elementwise: local hidden dim
  float c_state = 0.0f;

  for (int t = 0; t < TSEQ; ++t) {
    const _Float16* hc = (t & 1) ? h1 : h0;
    _Float16* hnx = (t & 1) ? h0 : h1;

    f32x4 acc = {0.f, 0.f, 0.f, 0.f};

    // x-part: K = 512
    if (use_xh) {
      const _Float16* xp = xh + ((size_t)arow * TSEQ + t) * INS + kq;
#pragma unroll 4
      for (int kk = 0; kk < INS / 32; ++kk) {
        half8 af = *(const half8*)(xp + kk * 32);
        half8 bf = *(const half8*)(&Wih_s[nn][kk * 32 + kq]);
        acc = __builtin_amdgcn_mfma_f32_16x16x32_f16(af, bf, acc, 0, 0, 0);
      }
    } else {
      const float* xp = x + ((size_t)arow * TSEQ + t) * INS + kq;
#pragma unroll 4
      for (int kk = 0; kk < INS / 32; ++kk) {
        half8 af;
#pragma unroll
        for (int j = 0; j < 8; ++j) af[j] = (_Float16)xp[kk * 32 + j];
        half8 bf = *(const half8*)(&Wih_s[nn][kk * 32 + kq]);
        acc = __builtin_amdgcn_mfma_f32_16x16x32_f16(af, bf, acc, 0, 0, 0);
      }
    }

    // h-part: K = 1024
    {
      const _Float16* hp = hc + arow * HID + kq;
#pragma unroll 4
      for (int kk = 0; kk < HID / 32; ++kk) {
        half8 af = *(const half8*)(hp + kk * 32);
        half8 bf = *(const half8*)(&Whh_s[nn][kk * 32 + kq]);
        acc = __builtin_amdgcn_mfma_f32_16x16x32_f16(af, bf, acc, 0, 0, 0);
      }
    }

    // scatter gate tile to LDS
    {
      int q = lane >> 4;
#pragma unroll
      for (int r = 0; r < 4; ++r) gates_s[m0 + q * 4 + r][nn] = acc[r];
    }
    __syncthreads();

    // pointwise LSTM cell (fp32), one (batch, dim) per thread
    float xi = gates_s[eb][ed] + bias_s[ed];
    float xf = gates_s[eb][4 + ed] + bias_s[4 + ed];
    float xg = gates_s[eb][8 + ed] + bias_s[8 + ed];
    float xo = gates_s[eb][12 + ed] + bias_s[12 + ed];
    float cn = sigf(xf) * c_state + sigf(xi) * tanhf(xg);
    c_state = cn;
    float hv = sigf(xo) * tanhf(cn);
    hnx[eb * HID + dim_base + ed] = (_Float16)hv;

    gbar(cnt, tgt); tgt += NWG;
  }

  // ---- classifier epilogue: out[b][o] = h_last . W_clf[o] + b_clf[o] ----
  // t=511 wrote into h0
  if (wg < BATCH && tid < NOUT) {
    const _Float16* hf = h0 + wg * HID;
    const float* wr = W_clf + tid * HID;
    float s = b_clf[tid];
    for (int k = 0; k < HID; ++k) s += (float)hf[k] * wr[k];
    out[wg * NOUT + tid] = s;
  }
}

extern "C" void kernel_launch(void* const* d_in, const int* in_sizes, int n_in,
                              void* d_out, int out_size, void* d_ws, size_t ws_size,
                              hipStream_t stream) {
  const float* x = (const float*)d_in[0];
  const float* W_ih = (const float*)d_in[1];
  const float* W_hh = (const float*)d_in[2];
  const float* b_ih = (const float*)d_in[3];
  const float* b_hh = (const float*)d_in[4];
  const float* W_clf = (const float*)d_in[5];
  const float* b_clf = (const float*)d_in[6];
  float* out = (float*)d_out;

  // zero barrier counter + h double buffer (ws is 0xAA-poisoned each call)
  hipMemsetAsync(d_ws, 0, 256 + 2 * BATCH * HID * 2, stream);

  // deterministic per-deployment: use f16 x-copy iff workspace is big enough
  int use_xh = (ws_size >= (512ull << 10) + (size_t)BATCH * TSEQ * INS * 2) ? 1 : 0;

  void* args[] = {(void*)&x,     (void*)&W_ih,  (void*)&W_hh, (void*)&b_ih,
                  (void*)&b_hh,  (void*)&W_clf, (void*)&b_clf, (void*)&out,
                  (void*)&d_ws,  (void*)&use_xh};
  hipLaunchCooperativeKernel((const void*)lstm_persist, dim3(NWG), dim3(NTHR),
                             args, 0, stream);
}

// Round 2
// 7299.707 us; speedup vs baseline: 1.8035x; 1.8035x over previous
//
#include <hip/hip_runtime.h>

#define TSEQ 512
#define BATCH 64
#define INS 512
#define HID 1024
#define NOUT 128
#define NWG 256
#define NTHR 256
#define HSTRIDE (BATCH * HID)  // f16 elements per h buffer (128 KB)
#define HBUF_OFF 4096

typedef _Float16 half8 __attribute__((ext_vector_type(8)));
typedef float f32x4 __attribute__((ext_vector_type(4)));

__device__ __forceinline__ float sigf(float v) { return 1.0f / (1.0f + __expf(-v)); }

// Monotonic counter barrier: RELAXED add + RELAXED spin (coherence-point ops,
// NO buffer_wbl2 / buffer_inv). h-store ordering comes from __syncthreads()'s
// vmcnt(0) drain before the add. Workgroup acquire fence = compiler ordering only.
__device__ __forceinline__ void gbar(unsigned* cnt, unsigned tgt) {
  __syncthreads();  // drains vmcnt(0): write-through h stores acked before arrival
  if (threadIdx.x == 0) {
    __hip_atomic_fetch_add(cnt, 1u, __ATOMIC_RELAXED, __HIP_MEMORY_SCOPE_AGENT);
    while (__hip_atomic_load(cnt, __ATOMIC_RELAXED, __HIP_MEMORY_SCOPE_AGENT) < tgt)
      __builtin_amdgcn_s_sleep(1);
  }
  __syncthreads();
  __builtin_amdgcn_fence(__ATOMIC_ACQUIRE, "workgroup");  // no cache op; blocks hoisting
}

__global__ __launch_bounds__(NTHR, 1) void lstm_persist(
    const float* __restrict__ x, const float* __restrict__ W_ih,
    const float* __restrict__ W_hh, const float* __restrict__ b_ih,
    const float* __restrict__ b_hh, const float* __restrict__ W_clf,
    const float* __restrict__ b_clf, float* __restrict__ out,
    void* ws, int nbuf, int do_fence) {
  __shared__ __align__(16) _Float16 Wih_s[16][INS + 8];
  __shared__ __align__(16) _Float16 Whh_s[16][HID + 8];
  __shared__ float gates_s[BATCH][17];  // pad 17: D-scatter conflicts <= ~2-way
  __shared__ float bias_s[16];

  const int tid = threadIdx.x;
  const int wg = blockIdx.x;
  const int dim_base = wg << 2;  // this WG owns hidden dims [dim_base, dim_base+4)

  unsigned* cnt = (unsigned*)ws;
  _Float16* hb = (_Float16*)((char*)ws + HBUF_OFF);

  // One-time agent acquire: discard any L2 lines left by the harness poison pass.
  __builtin_amdgcn_fence(__ATOMIC_ACQUIRE, "agent");

  // ---- stage weight slices to LDS (fp32 -> f16), col16 = gate*4 + local_dim ----
  for (int idx = tid; idx < 16 * INS; idx += NTHR) {
    int r = idx >> 9, k = idx & (INS - 1);
    int jg = ((r >> 2) << 10) + dim_base + (r & 3);
    Wih_s[r][k] = (_Float16)W_ih[jg * INS + k];
  }
  for (int idx = tid; idx < 16 * HID; idx += NTHR) {
    int r = idx >> 10, k = idx & (HID - 1);
    int jg = ((r >> 2) << 10) + dim_base + (r & 3);
    Whh_s[r][k] = (_Float16)W_hh[jg * HID + k];
  }
  if (tid < 16) {
    int jg = ((tid >> 2) << 10) + dim_base + (tid & 3);
    bias_s[tid] = b_ih[tid < 0 ? 0 : jg] + b_hh[jg];
  }
  __syncthreads();

  // MFMA lane mapping (16x16x32): A[m=lane&15][k=quad*8+j], B[n=lane&15][k=quad*8+j],
  // D: col=lane&15, row=quad*4+reg   [verified layouts m89/m91/m120]
  const int lane = tid & 63;
  const int wave = tid >> 6;
  const int m0 = wave << 4;         // 16-batch tile per wave
  const int nn = lane & 15;
  const int kq = (lane >> 4) << 3;  // 0,8,16,24
  const int arow = m0 + nn;
  const int eb = tid >> 2;  // elementwise: batch
  const int ed = tid & 3;   // elementwise: local hidden dim

  // x-projection for one timestep (K=512), reads f32 x, cvt to f16 in-register
  auto xpart = [&](int t) -> f32x4 {
    f32x4 a = {0.f, 0.f, 0.f, 0.f};
    const float* xp = x + ((size_t)arow * TSEQ + t) * INS + kq;
#pragma unroll 4
    for (int kk = 0; kk < INS / 32; ++kk) {
      float4 lo = *(const float4*)(xp + kk * 32);
      float4 hi = *(const float4*)(xp + kk * 32 + 4);
      half8 af = {(_Float16)lo.x, (_Float16)lo.y, (_Float16)lo.z, (_Float16)lo.w,
                  (_Float16)hi.x, (_Float16)hi.y, (_Float16)hi.z, (_Float16)hi.w};
      half8 bf = *(const half8*)(&Wih_s[nn][kk * 32 + kq]);
      a = __builtin_amdgcn_mfma_f32_16x16x32_f16(af, bf, a, 0, 0, 0);
    }
    return a;
  };

  float c_state = 0.0f;
  f32x4 accx = xpart(0);
  unsigned tgt = NWG;

  for (int t = 0; t < TSEQ; ++t) {
    // rotating buffers (nbuf=513): fresh addresses each step -> plain cached
    // loads can never see a stale L2 line; 32 WGs/XCD share the fill.
    const _Float16* hc = hb + (size_t)(nbuf == 2 ? (t & 1) : t) * HSTRIDE;
    _Float16* hn = (_Float16*)hb + (size_t)(nbuf == 2 ? ((t + 1) & 1) : (t + 1)) * HSTRIDE;

    // h-part: K = 1024 (plain b128 loads, L2-cacheable)
    f32x4 acc = accx;
    {
      const _Float16* hp = hc + arow * HID + kq;
#pragma unroll 8
      for (int kk = 0; kk < HID / 32; ++kk) {
        half8 af = *(const half8*)(hp + kk * 32);
        half8 bf = *(const half8*)(&Whh_s[nn][kk * 32 + kq]);
        acc = __builtin_amdgcn_mfma_f32_16x16x32_f16(af, bf, acc, 0, 0, 0);
      }
    }

    // scatter gate tile to LDS
    {
      int q = lane >> 4;
#pragma unroll
      for (int r = 0; r < 4; ++r) gates_s[m0 + q * 4 + r][nn] = acc[r];
    }
    __syncthreads();

    // pointwise LSTM cell (fp32), one (batch, dim) per thread
    float xi = gates_s[eb][ed] + bias_s[ed];
    float xf = gates_s[eb][4 + ed] + bias_s[4 + ed];
    float xg = gates_s[eb][8 + ed] + bias_s[8 + ed];
    float xo = gates_s[eb][12 + ed] + bias_s[12 + ed];
    float cn = sigf(xf) * c_state + sigf(xi) * tanhf(xg);
    c_state = cn;
    float hv = sigf(xo) * tanhf(cn);

    // pack quad's 4 f16 into 8B, one write-through store per batch row
    unsigned hw = (unsigned)__builtin_bit_cast(unsigned short, (_Float16)hv);
    unsigned o1 = __shfl_down(hw, 1);
    unsigned o2 = __shfl_down(hw, 2);
    unsigned o3 = __shfl_down(hw, 3);
    if (ed == 0) {
      unsigned lo = hw | (o1 << 16), hi = o2 | (o3 << 16);
      unsigned long long u = ((unsigned long long)hi << 32) | lo;
      __hip_atomic_store((unsigned long long*)(hn + eb * HID + dim_base), u,
                         __ATOMIC_RELAXED, __HIP_MEMORY_SCOPE_AGENT);
    }

    // pipeline: x-projection for t+1 hides under barrier skew
    int tn = t + 1 < TSEQ ? t + 1 : t;
    accx = xpart(tn);

    gbar(cnt, tgt);
    tgt += NWG;
    if (do_fence) __builtin_amdgcn_fence(__ATOMIC_ACQUIRE, "agent");  // tier C only
  }

  // ---- classifier epilogue: out[b][o] = h_last . W_clf[o] + b_clf[o] ----
  const _Float16* hf = hb + (size_t)(nbuf == 2 ? 0 : TSEQ) * HSTRIDE;
  if (wg < BATCH && tid < NOUT) {
    const _Float16* hr = hf + wg * HID;
    const float* wr = W_clf + tid * HID;
    float s = b_clf[tid];
    for (int k = 0; k < HID; ++k) s += (float)hr[k] * wr[k];
    out[wg * NOUT + tid] = s;
  }
}

extern "C" void kernel_launch(void* const* d_in, const int* in_sizes, int n_in,
                              void* d_out, int out_size, void* d_ws, size_t ws_size,
                              hipStream_t stream) {
  const float* x = (const float*)d_in[0];
  const float* W_ih = (const float*)d_in[1];
  const float* W_hh = (const float*)d_in[2];
  const float* b_ih = (const float*)d_in[3];
  const float* b_hh = (const float*)d_in[4];
  const float* W_clf = (const float*)d_in[5];
  const float* b_clf = (const float*)d_in[6];
  float* out = (float*)d_out;

  // zero barrier counter + h buffer 0 (ws is 0xAA-poisoned each call)
  hipMemsetAsync(d_ws, 0, HBUF_OFF + HSTRIDE * 2, stream);

  // tier A: 513 rotating h buffers (no per-step cache maintenance)
  size_t need_rot = (size_t)HBUF_OFF + 513ull * HSTRIDE * 2;
  int nbuf = (ws_size >= need_rot) ? 513 : 2;
  int do_fence = (nbuf == 2) ? 1 : 0;

  void* args[] = {(void*)&x,    (void*)&W_ih,  (void*)&W_hh,  (void*)&b_ih,
                  (void*)&b_hh, (void*)&W_clf, (void*)&b_clf, (void*)&out,
                  (void*)&d_ws, (void*)&nbuf,  (void*)&do_fence};
  hipLaunchCooperativeKernel((const void*)lstm_persist, dim3(NWG), dim3(NTHR),
                             args, 0, stream);
}

// Round 3
// 4554.420 us; speedup vs baseline: 2.8906x; 1.6028x over previous
//
#include <hip/hip_runtime.h>

#define TSEQ 512
#define BATCH 64
#define INS 512
#define HID 1024
#define NOUT 128
#define NWG 256
#define NTHR 256
#define HSTRIDE (BATCH * HID)  // f16 elements per h buffer (128 KB)
#define HBUF_OFF 16384
#define LEAVES 16
#define LSIZE 16
#define LSHIFT 4

typedef _Float16 half8 __attribute__((ext_vector_type(8)));
typedef float f32x4 __attribute__((ext_vector_type(4)));

__device__ __forceinline__ float sigf(float v) { return 1.0f / (1.0f + __expf(-v)); }

// ---- hierarchical monotonic barrier (no cache-maintenance ops) ----
// arrive: leaf fetch_add (16 lines x 16 WGs); leaf-last bumps root; global-last
// broadcasts per-leaf "go" words. wait: spin own leaf's go line (16 pollers/line).
__device__ __forceinline__ void bar_arrive(unsigned* leafp, unsigned* root,
                                           unsigned* gob, int step) {
  __syncthreads();  // vmcnt(0) drain: h write-through stores acked (globally visible)
  if (threadIdx.x == 0) {
    unsigned old = __hip_atomic_fetch_add(leafp, 1u, __ATOMIC_RELAXED,
                                          __HIP_MEMORY_SCOPE_AGENT);
    if ((old & (LSIZE - 1)) == LSIZE - 1) {  // last arrival of this leaf this step
      unsigned rold = __hip_atomic_fetch_add(root, 1u, __ATOMIC_RELAXED,
                                             __HIP_MEMORY_SCOPE_AGENT);
      if (rold == (unsigned)step * LEAVES + (LEAVES - 1)) {
        #pragma unroll
        for (int l = 0; l < LEAVES; ++l)
          __hip_atomic_store(gob + l * 64, (unsigned)(step + 1),
                             __ATOMIC_RELAXED, __HIP_MEMORY_SCOPE_AGENT);
      }
    }
  }
}

__device__ __forceinline__ void bar_wait(unsigned* goown, int step) {
  if (threadIdx.x == 0) {
    while (__hip_atomic_load(goown, __ATOMIC_RELAXED,
                             __HIP_MEMORY_SCOPE_AGENT) < (unsigned)(step + 1))
      __builtin_amdgcn_s_sleep(2);
  }
  __syncthreads();
  __builtin_amdgcn_fence(__ATOMIC_ACQUIRE, "workgroup");  // compiler ordering only
}

__global__ __launch_bounds__(NTHR, 1) void lstm_persist(
    const float* __restrict__ x, const float* __restrict__ W_ih,
    const float* __restrict__ W_hh, const float* __restrict__ b_ih,
    const float* __restrict__ b_hh, const float* __restrict__ W_clf,
    const float* __restrict__ b_clf, float* __restrict__ out,
    void* ws, int nbuf, int do_fence) {
  __shared__ __align__(16) _Float16 Wih_s[16][INS + 8];
  __shared__ __align__(16) _Float16 Whh_s[16][HID + 8];
  __shared__ float gates_s[BATCH][17];
  __shared__ float bias_s[16];

  const int tid = threadIdx.x;
  const int wg = blockIdx.x;
  const int dim_base = wg << 2;  // this WG owns hidden dims [dim_base, dim_base+4)

  unsigned* root = (unsigned*)ws;
  unsigned* leafp = (unsigned*)((char*)ws + 256) + (wg >> LSHIFT) * 64;
  unsigned* gob = (unsigned*)((char*)ws + 256 + LEAVES * 256);
  unsigned* goown = gob + (wg >> LSHIFT) * 64;
  _Float16* hb = (_Float16*)((char*)ws + HBUF_OFF);

  __builtin_amdgcn_fence(__ATOMIC_ACQUIRE, "agent");  // one-time: drop poison lines

  // ---- stage weight slices to LDS (fp32 -> f16), col16 = gate*4 + local_dim ----
  for (int idx = tid; idx < 16 * INS; idx += NTHR) {
    int r = idx >> 9, k = idx & (INS - 1);
    int jg = ((r >> 2) << 10) + dim_base + (r & 3);
    Wih_s[r][k] = (_Float16)W_ih[jg * INS + k];
  }
  for (int idx = tid; idx < 16 * HID; idx += NTHR) {
    int r = idx >> 10, k = idx & (HID - 1);
    int jg = ((r >> 2) << 10) + dim_base + (r & 3);
    Whh_s[r][k] = (_Float16)W_hh[jg * HID + k];
  }
  if (tid < 16) {
    int jg = ((tid >> 2) << 10) + dim_base + (tid & 3);
    bias_s[tid] = b_ih[jg] + b_hh[jg];
  }
  __syncthreads();

  // MFMA lane mapping (16x16x32): A[m=lane&15][k=quad*8+j], B[n=lane&15][k=quad*8+j],
  // D: col=lane&15, row=quad*4+reg   [verified layouts m89/m91/m120]
  const int lane = tid & 63;
  const int wave = tid >> 6;
  const int m0 = wave << 4;
  const int nn = lane & 15;
  const int kq = (lane >> 4) << 3;
  const int arow = m0 + nn;
  const int eb = tid >> 2;
  const int ed = tid & 3;

  auto xpart = [&](int t) -> f32x4 {
    f32x4 a = {0.f, 0.f, 0.f, 0.f};
    const float* xp = x + ((size_t)arow * TSEQ + t) * INS + kq;
#pragma unroll 4
    for (int kk = 0; kk < INS / 32; ++kk) {
      float4 lo = *(const float4*)(xp + kk * 32);
      float4 hi = *(const float4*)(xp + kk * 32 + 4);
      half8 af = {(_Float16)lo.x, (_Float16)lo.y, (_Float16)lo.z, (_Float16)lo.w,
                  (_Float16)hi.x, (_Float16)hi.y, (_Float16)hi.z, (_Float16)hi.w};
      half8 bf = *(const half8*)(&Wih_s[nn][kk * 32 + kq]);
      a = __builtin_amdgcn_mfma_f32_16x16x32_f16(af, bf, a, 0, 0, 0);
    }
    return a;
  };

  float c_state = 0.0f;
  f32x4 accx = xpart(0);

  for (int t = 0; t < TSEQ; ++t) {
    const _Float16* hc = hb + (size_t)(nbuf == 2 ? (t & 1) : t) * HSTRIDE;
    _Float16* hn = (_Float16*)hb + (size_t)(nbuf == 2 ? ((t + 1) & 1) : (t + 1)) * HSTRIDE;

    // h-part: K=1024, two independent accumulator chains (halve dep latency)
    f32x4 a0 = accx, a1 = {0.f, 0.f, 0.f, 0.f};
    {
      const _Float16* hp = hc + arow * HID + kq;
#pragma unroll
      for (int kk = 0; kk < HID / 32; kk += 2) {
        half8 af0 = *(const half8*)(hp + kk * 32);
        half8 bf0 = *(const half8*)(&Whh_s[nn][kk * 32 + kq]);
        half8 af1 = *(const half8*)(hp + (kk + 1) * 32);
        half8 bf1 = *(const half8*)(&Whh_s[nn][(kk + 1) * 32 + kq]);
        a0 = __builtin_amdgcn_mfma_f32_16x16x32_f16(af0, bf0, a0, 0, 0, 0);
        a1 = __builtin_amdgcn_mfma_f32_16x16x32_f16(af1, bf1, a1, 0, 0, 0);
      }
    }
    f32x4 acc = a0 + a1;

    // scatter gate tile to LDS
    {
      int q = lane >> 4;
#pragma unroll
      for (int r = 0; r < 4; ++r) gates_s[m0 + q * 4 + r][nn] = acc[r];
    }
    __syncthreads();

    // pointwise LSTM cell (fp32)
    float xi = gates_s[eb][ed] + bias_s[ed];
    float xf = gates_s[eb][4 + ed] + bias_s[4 + ed];
    float xg = gates_s[eb][8 + ed] + bias_s[8 + ed];
    float xo = gates_s[eb][12 + ed] + bias_s[12 + ed];
    float cn = sigf(xf) * c_state + sigf(xi) * tanhf(xg);
    c_state = cn;
    float hv = sigf(xo) * tanhf(cn);

    // pack quad's 4 f16 into 8B, one write-through store per batch row
    unsigned hw = (unsigned)__builtin_bit_cast(unsigned short, (_Float16)hv);
    unsigned o1 = __shfl_down(hw, 1);
    unsigned o2 = __shfl_down(hw, 2);
    unsigned o3 = __shfl_down(hw, 3);
    if (ed == 0) {
      unsigned lo = hw | (o1 << 16), hi = o2 | (o3 << 16);
      unsigned long long u = ((unsigned long long)hi << 32) | lo;
      __hip_atomic_store((unsigned long long*)(hn + eb * HID + dim_base), u,
                         __ATOMIC_RELAXED, __HIP_MEMORY_SCOPE_AGENT);
    }

    bar_arrive(leafp, root, gob, t);          // arrival first...
    int tn = t + 1 < TSEQ ? t + 1 : t;
    accx = xpart(tn);                          // ...x-proj hides under barrier skew
    bar_wait(goown, t);
    if (do_fence) __builtin_amdgcn_fence(__ATOMIC_ACQUIRE, "agent");  // tier B only
  }

  // ---- classifier epilogue, spread over all 256 WGs ----
  // wg -> batch b = wg&63, output block ob = (wg>>6)*32; 8 threads per output
  {
    const _Float16* hf = hb + (size_t)(nbuf == 2 ? 0 : TSEQ) * HSTRIDE;
    int b = wg & 63;
    int ob = (wg >> 6) << 5;
    int o = ob + (tid >> 3);
    int ks = tid & 7;
    const _Float16* hr = hf + b * HID;
    const float* wr = W_clf + (size_t)o * HID;
    float s = 0.f;
    for (int k = ks; k < HID; k += 8) s += (float)hr[k] * wr[k];
    s += __shfl_down(s, 4, 8);
    s += __shfl_down(s, 2, 8);
    s += __shfl_down(s, 1, 8);
    if (ks == 0) out[b * NOUT + o] = s + b_clf[o];
  }
}

extern "C" void kernel_launch(void* const* d_in, const int* in_sizes, int n_in,
                              void* d_out, int out_size, void* d_ws, size_t ws_size,
                              hipStream_t stream) {
  const float* x = (const float*)d_in[0];
  const float* W_ih = (const float*)d_in[1];
  const float* W_hh = (const float*)d_in[2];
  const float* b_ih = (const float*)d_in[3];
  const float* b_hh = (const float*)d_in[4];
  const float* W_clf = (const float*)d_in[5];
  const float* b_clf = (const float*)d_in[6];
  float* out = (float*)d_out;

  // zero barrier lines + h buffer 0 (ws is 0xAA-poisoned each call)
  hipMemsetAsync(d_ws, 0, HBUF_OFF + HSTRIDE * 2, stream);

  // tier A: 513 rotating h buffers (no per-step cache maintenance)
  size_t need_rot = (size_t)HBUF_OFF + 513ull * HSTRIDE * 2;
  int nbuf = (ws_size >= need_rot) ? 513 : 2;
  int do_fence = (nbuf == 2) ? 1 : 0;

  void* args[] = {(void*)&x,    (void*)&W_ih,  (void*)&W_hh,  (void*)&b_ih,
                  (void*)&b_hh, (void*)&W_clf, (void*)&b_clf, (void*)&out,
                  (void*)&d_ws, (void*)&nbuf,  (void*)&do_fence};
  hipLaunchCooperativeKernel((const void*)lstm_persist, dim3(NWG), dim3(NTHR),
                             args, 0, stream);
}

// Round 4
// 4518.545 us; speedup vs baseline: 2.9135x; 1.0079x over previous
//
#include <hip/hip_runtime.h>

#define TSEQ 512
#define BATCH 64
#define INS 512
#define HID 1024
#define NOUT 128
#define NWG 256
#define NTHR 256
#define HSTRIDE (BATCH * HID)  // f16 elements per h buffer (128 KB)
#define HBUF_OFF 32768

typedef _Float16 half8 __attribute__((ext_vector_type(8)));
typedef float f32x4 __attribute__((ext_vector_type(4)));

__device__ __forceinline__ float sigf(float v) {
  return __builtin_amdgcn_rcpf(1.0f + __expf(-v));
}
__device__ __forceinline__ float tanh_fast(float v) {
  float e = __expf(2.0f * fabsf(v));             // large |v|: e=inf -> t=1 (safe)
  float t = 1.0f - 2.0f * __builtin_amdgcn_rcpf(e + 1.0f);
  return copysignf(t, v);
}

__global__ __launch_bounds__(NTHR, 1) void lstm_persist(
    const float* __restrict__ x, const float* __restrict__ W_ih,
    const float* __restrict__ W_hh, const float* __restrict__ b_ih,
    const float* __restrict__ b_hh, const float* __restrict__ W_clf,
    const float* __restrict__ b_clf, float* __restrict__ out,
    void* ws, int nbuf, int do_fence) {
  __shared__ __align__(16) _Float16 Wih_s[16][INS + 8];
  __shared__ __align__(16) _Float16 Whh_s[16][HID + 8];
  __shared__ float gates_s[BATCH][17];
  __shared__ float bias_s[16];

  const int tid = threadIdx.x;
  const int wg = blockIdx.x;
  const int dim_base = wg << 2;  // this WG owns hidden dims [dim_base, dim_base+4)

  // arrival words: arr[w] (dense, 1 KB = 8 lines). No RMW anywhere in the barrier.
  unsigned* arr = (unsigned*)ws;
  _Float16* hb = (_Float16*)((char*)ws + HBUF_OFF);

  __builtin_amdgcn_fence(__ATOMIC_ACQUIRE, "agent");  // one-time: drop poison lines

  // ---- stage weight slices to LDS (fp32 -> f16), col16 = gate*4 + local_dim ----
  for (int idx = tid; idx < 16 * INS; idx += NTHR) {
    int r = idx >> 9, k = idx & (INS - 1);
    int jg = ((r >> 2) << 10) + dim_base + (r & 3);
    Wih_s[r][k] = (_Float16)W_ih[jg * INS + k];
  }
  for (int idx = tid; idx < 16 * HID; idx += NTHR) {
    int r = idx >> 10, k = idx & (HID - 1);
    int jg = ((r >> 2) << 10) + dim_base + (r & 3);
    Whh_s[r][k] = (_Float16)W_hh[jg * HID + k];
  }
  if (tid < 16) {
    int jg = ((tid >> 2) << 10) + dim_base + (tid & 3);
    bias_s[tid] = b_ih[jg] + b_hh[jg];
  }
  __syncthreads();

  // MFMA lane mapping (16x16x32): A[m=lane&15][k=quad*8+j], B[n=lane&15][k=quad*8+j],
  // D: col=lane&15, row=quad*4+reg   [verified layouts m89/m91/m120]
  const int lane = tid & 63;
  const int wave = tid >> 6;
  const int m0 = wave << 4;
  const int nn = lane & 15;
  const int kq = (lane >> 4) << 3;
  const int arow = m0 + nn;
  const int eb = tid >> 2;  // pointwise row — provably within own wave's m-tile
  const int ed = tid & 3;

  auto xpart = [&](int t) -> f32x4 {
    f32x4 a = {0.f, 0.f, 0.f, 0.f};
    const float* xp = x + ((size_t)arow * TSEQ + t) * INS + kq;
#pragma unroll 4
    for (int kk = 0; kk < INS / 32; ++kk) {
      float4 lo = *(const float4*)(xp + kk * 32);
      float4 hi = *(const float4*)(xp + kk * 32 + 4);
      half8 af = {(_Float16)lo.x, (_Float16)lo.y, (_Float16)lo.z, (_Float16)lo.w,
                  (_Float16)hi.x, (_Float16)hi.y, (_Float16)hi.z, (_Float16)hi.w};
      half8 bf = *(const half8*)(&Wih_s[nn][kk * 32 + kq]);
      a = __builtin_amdgcn_mfma_f32_16x16x32_f16(af, bf, a, 0, 0, 0);
    }
    return a;
  };

  float c_state = 0.0f;
  f32x4 accx = xpart(0);

  for (int t = 0; t < TSEQ; ++t) {
    const _Float16* hc = hb + (size_t)(nbuf == 2 ? (t & 1) : t) * HSTRIDE;
    _Float16* hn = (_Float16*)hb + (size_t)(nbuf == 2 ? ((t + 1) & 1) : (t + 1)) * HSTRIDE;

    // h-part: K=1024, two independent accumulator chains
    f32x4 a0 = accx, a1 = {0.f, 0.f, 0.f, 0.f};
    {
      const _Float16* hp = hc + arow * HID + kq;
#pragma unroll
      for (int kk = 0; kk < HID / 32; kk += 2) {
        half8 af0 = *(const half8*)(hp + kk * 32);
        half8 bf0 = *(const half8*)(&Whh_s[nn][kk * 32 + kq]);
        half8 af1 = *(const half8*)(hp + (kk + 1) * 32);
        half8 bf1 = *(const half8*)(&Whh_s[nn][(kk + 1) * 32 + kq]);
        a0 = __builtin_amdgcn_mfma_f32_16x16x32_f16(af0, bf0, a0, 0, 0, 0);
        a1 = __builtin_amdgcn_mfma_f32_16x16x32_f16(af1, bf1, a1, 0, 0, 0);
      }
    }
    f32x4 acc = a0 + a1;

    // wave-local gate transpose through LDS (rows m0..m0+15 belong to this wave;
    // no cross-wave traffic -> s_waitcnt lgkmcnt(0)替代 __syncthreads)
    {
      int q = lane >> 4;
#pragma unroll
      for (int r = 0; r < 4; ++r) gates_s[m0 + q * 4 + r][nn] = acc[r];
    }
    __asm__ volatile("s_waitcnt lgkmcnt(0)" ::: "memory");

    // pointwise LSTM cell (fp32)
    float xi = gates_s[eb][ed] + bias_s[ed];
    float xf = gates_s[eb][4 + ed] + bias_s[4 + ed];
    float xg = gates_s[eb][8 + ed] + bias_s[8 + ed];
    float xo = gates_s[eb][12 + ed] + bias_s[12 + ed];
    float cn = sigf(xf) * c_state + sigf(xi) * tanh_fast(xg);
    c_state = cn;
    float hv = sigf(xo) * tanh_fast(cn);

    // pack quad's 4 f16 into 8B, one write-through store per batch row
    unsigned hw = (unsigned)__builtin_bit_cast(unsigned short, (_Float16)hv);
    unsigned o1 = __shfl_down(hw, 1);
    unsigned o2 = __shfl_down(hw, 2);
    unsigned o3 = __shfl_down(hw, 3);
    if (ed == 0) {
      unsigned lo = hw | (o1 << 16), hi = o2 | (o3 << 16);
      unsigned long long u = ((unsigned long long)hi << 32) | lo;
      __hip_atomic_store((unsigned long long*)(hn + eb * HID + dim_base), u,
                         __ATOMIC_RELAXED, __HIP_MEMORY_SCOPE_AGENT);
    }

    // ---- barrier: store-only arrival + all-threads direct poll ----
    __syncthreads();  // per-wave vmcnt(0) drain: all h stores globally visible
    if (tid == 0)
      __hip_atomic_store(arr + wg, (unsigned)(t + 1), __ATOMIC_RELAXED,
                         __HIP_MEMORY_SCOPE_AGENT);

    int tn = t + 1 < TSEQ ? t + 1 : t;
    accx = xpart(tn);  // overlap with arrival propagation

    {
      const unsigned T = (unsigned)(t + 1);
      int ok;
      do {
        unsigned v = __hip_atomic_load(arr + tid, __ATOMIC_RELAXED,
                                       __HIP_MEMORY_SCOPE_AGENT);
        ok = (v >= T);
        if (!ok) __builtin_amdgcn_s_sleep(1);
      } while (!__syncthreads_and(ok));
    }
    __builtin_amdgcn_fence(__ATOMIC_ACQUIRE, "workgroup");  // compiler ordering only
    if (do_fence) __builtin_amdgcn_fence(__ATOMIC_ACQUIRE, "agent");  // tier B only
  }

  // ---- classifier epilogue, spread over all 256 WGs ----
  {
    const _Float16* hf = hb + (size_t)(nbuf == 2 ? 0 : TSEQ) * HSTRIDE;
    int b = wg & 63;
    int ob = (wg >> 6) << 5;
    int o = ob + (tid >> 3);
    int ks = tid & 7;
    const _Float16* hr = hf + b * HID;
    const float* wr = W_clf + (size_t)o * HID;
    float s = 0.f;
    for (int k = ks; k < HID; k += 8) s += (float)hr[k] * wr[k];
    s += __shfl_down(s, 4, 8);
    s += __shfl_down(s, 2, 8);
    s += __shfl_down(s, 1, 8);
    if (ks == 0) out[b * NOUT + o] = s + b_clf[o];
  }
}

extern "C" void kernel_launch(void* const* d_in, const int* in_sizes, int n_in,
                              void* d_out, int out_size, void* d_ws, size_t ws_size,
                              hipStream_t stream) {
  const float* x = (const float*)d_in[0];
  const float* W_ih = (const float*)d_in[1];
  const float* W_hh = (const float*)d_in[2];
  const float* b_ih = (const float*)d_in[3];
  const float* b_hh = (const float*)d_in[4];
  const float* W_clf = (const float*)d_in[5];
  const float* b_clf = (const float*)d_in[6];
  float* out = (float*)d_out;

  // zero arrival words + h buffer 0 (ws is 0xAA-poisoned each call)
  hipMemsetAsync(d_ws, 0, HBUF_OFF + HSTRIDE * 2, stream);

  // tier A: 513 rotating h buffers (no per-step cache maintenance)
  size_t need_rot = (size_t)HBUF_OFF + 513ull * HSTRIDE * 2;
  int nbuf = (ws_size >= need_rot) ? 513 : 2;
  int do_fence = (nbuf == 2) ? 1 : 0;

  void* args[] = {(void*)&x,    (void*)&W_ih,  (void*)&W_hh,  (void*)&b_ih,
                  (void*)&b_hh, (void*)&W_clf, (void*)&b_clf, (void*)&out,
                  (void*)&d_ws, (void*)&nbuf,  (void*)&do_fence};
  hipLaunchCooperativeKernel((const void*)lstm_persist, dim3(NWG), dim3(NTHR),
                             args, 0, stream);
}

// Round 6
// 3679.934 us; speedup vs baseline: 3.5775x; 1.2279x over previous
//
#include <hip/hip_runtime.h>

#define TSEQ 512
#define BATCH 64
#define INS 512
#define HID 1024
#define NOUT 128
#define NWG 256
#define NTHR 256
#define HSTRIDE (BATCH * HID)  // f16 elements per h slot (128 KB)
#define FLAGS_BYTES 32768
#define XH_ELEMS ((size_t)BATCH * TSEQ * INS)
#define XH_BYTES (XH_ELEMS * 2)

typedef _Float16 half8 __attribute__((ext_vector_type(8)));
typedef _Float16 half4v __attribute__((ext_vector_type(4)));
typedef float f32x4 __attribute__((ext_vector_type(4)));

__device__ __forceinline__ float sigf(float v) {
  return __builtin_amdgcn_rcpf(1.0f + __expf(-v));
}
__device__ __forceinline__ float tanh_fast(float v) {
  float e = __expf(2.0f * fabsf(v));  // large |v|: e=inf -> t=1 (safe)
  float t = 1.0f - 2.0f * __builtin_amdgcn_rcpf(e + 1.0f);
  return copysignf(t, v);
}

__global__ __launch_bounds__(NTHR, 1) void lstm_persist(
    const float* __restrict__ x, const float* __restrict__ W_ih,
    const float* __restrict__ W_hh, const float* __restrict__ b_ih,
    const float* __restrict__ b_hh, const float* __restrict__ W_clf,
    const float* __restrict__ b_clf, float* __restrict__ out,
    void* ws, int nbuf, int use_xh, int do_fence) {
  __shared__ __align__(16) _Float16 Wih_s[16][INS + 8];
  __shared__ __align__(16) _Float16 Whh_s[16][HID + 8];
  __shared__ float gates_s[BATCH][17];
  __shared__ float bias_s[16];

  const int tid = threadIdx.x;
  const int wg = blockIdx.x;
  const int dim_base = wg << 2;  // this WG owns hidden dims [dim_base, dim_base+4)

  unsigned* flags = (unsigned*)ws;
  _Float16* xh = (_Float16*)((char*)ws + FLAGS_BYTES);
  _Float16* hb = xh + (use_xh ? XH_ELEMS : 0);

  __builtin_amdgcn_fence(__ATOMIC_ACQUIRE, "agent");  // one-time: drop poison lines

  // ---- stage weight slices to LDS (fp32 -> f16), col16 = gate*4 + local_dim ----
  for (int idx = tid; idx < 16 * INS; idx += NTHR) {
    int r = idx >> 9, k = idx & (INS - 1);
    int jg = ((r >> 2) << 10) + dim_base + (r & 3);
    Wih_s[r][k] = (_Float16)W_ih[jg * INS + k];
  }
  for (int idx = tid; idx < 16 * HID; idx += NTHR) {
    int r = idx >> 10, k = idx & (HID - 1);
    int jg = ((r >> 2) << 10) + dim_base + (r & 3);
    Whh_s[r][k] = (_Float16)W_hh[jg * HID + k];
  }
  if (tid < 16) {
    int jg = ((tid >> 2) << 10) + dim_base + (tid & 3);
    bias_s[tid] = b_ih[jg] + b_hh[jg];
  }
  __syncthreads();

  // ---- one-time: convert x to f16 (grid-strided), publish with one wbL2 ----
  if (use_xh) {
    const float4* xv = (const float4*)x;
    const int n4 = (int)(XH_ELEMS / 4);
    for (int i = wg * NTHR + tid; i < n4; i += NWG * NTHR) {
      float4 v = xv[i];
      half4v hv = {(_Float16)v.x, (_Float16)v.y, (_Float16)v.z, (_Float16)v.w};
      *(half4v*)(xh + (size_t)i * 4) = hv;
    }
    __builtin_amdgcn_fence(__ATOMIC_RELEASE, "agent");
  }

  // ---- prolog flag barrier (tag 1), round-4-proven all-thread poll ----
  __syncthreads();
  if (tid == 0)
    __hip_atomic_store(flags + wg, 1u, __ATOMIC_RELAXED, __HIP_MEMORY_SCOPE_AGENT);
  {
    int ok;
    do {
      unsigned v = __hip_atomic_load(flags + tid, __ATOMIC_RELAXED,
                                     __HIP_MEMORY_SCOPE_AGENT);
      ok = (v >= 1u);
      if (!ok) __builtin_amdgcn_s_sleep(1);
    } while (!__syncthreads_and(ok));
  }
  __builtin_amdgcn_fence(__ATOMIC_ACQUIRE, "workgroup");

  // MFMA lane mapping (16x16x32): A[m=lane&15][k=quad*8+j], B[n=lane&15][k=quad*8+j],
  // D: col=lane&15, row=quad*4+reg   [verified layouts m89/m91/m120]
  const int lane = tid & 63;
  const int wave = tid >> 6;
  const int m0 = wave << 4;
  const int nn = lane & 15;
  const int kq = (lane >> 4) << 3;
  const int arow = m0 + nn;
  const int eb = tid >> 2;  // pointwise row — within own wave's m-tile
  const int ed = tid & 3;

  // x-projection: 16 batched b128 loads (MLP), weights from LDS, 2 acc chains
  auto xpart = [&](int t) -> f32x4 {
    f32x4 a = {0.f, 0.f, 0.f, 0.f}, a1 = {0.f, 0.f, 0.f, 0.f};
    if (use_xh) {
      const _Float16* xp = xh + ((size_t)arow * TSEQ + t) * INS + kq;
      half8 xa[16];
#pragma unroll
      for (int i = 0; i < 16; ++i) xa[i] = *(const half8*)(xp + i * 32);
#pragma unroll
      for (int i = 0; i < 16; i += 2) {
        half8 b0 = *(const half8*)(&Wih_s[nn][i * 32 + kq]);
        half8 b1 = *(const half8*)(&Wih_s[nn][(i + 1) * 32 + kq]);
        a = __builtin_amdgcn_mfma_f32_16x16x32_f16(xa[i], b0, a, 0, 0, 0);
        a1 = __builtin_amdgcn_mfma_f32_16x16x32_f16(xa[i + 1], b1, a1, 0, 0, 0);
      }
    } else {
      const float* xp = x + ((size_t)arow * TSEQ + t) * INS + kq;
#pragma unroll
      for (int i = 0; i < 16; i += 2) {
        float4 l0 = *(const float4*)(xp + i * 32);
        float4 h0 = *(const float4*)(xp + i * 32 + 4);
        float4 l1 = *(const float4*)(xp + (i + 1) * 32);
        float4 h1 = *(const float4*)(xp + (i + 1) * 32 + 4);
        half8 f0 = half8{(_Float16)l0.x, (_Float16)l0.y, (_Float16)l0.z, (_Float16)l0.w,
                         (_Float16)h0.x, (_Float16)h0.y, (_Float16)h0.z, (_Float16)h0.w};
        half8 f1 = half8{(_Float16)l1.x, (_Float16)l1.y, (_Float16)l1.z, (_Float16)l1.w,
                         (_Float16)h1.x, (_Float16)h1.y, (_Float16)h1.z, (_Float16)h1.w};
        half8 b0 = *(const half8*)(&Wih_s[nn][i * 32 + kq]);
        half8 b1 = *(const half8*)(&Wih_s[nn][(i + 1) * 32 + kq]);
        a = __builtin_amdgcn_mfma_f32_16x16x32_f16(f0, b0, a, 0, 0, 0);
        a1 = __builtin_amdgcn_mfma_f32_16x16x32_f16(f1, b1, a1, 0, 0, 0);
      }
    }
    return a + a1;
  };

  float c_state = 0.0f;
  f32x4 accx = xpart(0);

  for (int t = 0; t < TSEQ; ++t) {
    const _Float16* hc = hb + (size_t)(nbuf == 2 ? (t & 1) : t) * HSTRIDE;
    _Float16* hn = (_Float16*)hb + (size_t)(nbuf == 2 ? ((t + 1) & 1) : (t + 1)) * HSTRIDE;

    // h-part: ALL 32 A-fragments batched -> 32 loads in flight, one latency hit
    f32x4 a0 = accx, a1 = {0.f, 0.f, 0.f, 0.f};
    {
      const _Float16* hp = hc + arow * HID + kq;
      half8 ha[32];
#pragma unroll
      for (int i = 0; i < 32; ++i) ha[i] = *(const half8*)(hp + i * 32);
#pragma unroll
      for (int i = 0; i < 32; i += 2) {
        half8 b0 = *(const half8*)(&Whh_s[nn][i * 32 + kq]);
        half8 b1 = *(const half8*)(&Whh_s[nn][(i + 1) * 32 + kq]);
        a0 = __builtin_amdgcn_mfma_f32_16x16x32_f16(ha[i], b0, a0, 0, 0, 0);
        a1 = __builtin_amdgcn_mfma_f32_16x16x32_f16(ha[i + 1], b1, a1, 0, 0, 0);
      }
    }
    f32x4 acc = a0 + a1;

    // wave-local gate transpose through LDS (rows m0..m0+15 are this wave's)
    {
      int q = lane >> 4;
#pragma unroll
      for (int r = 0; r < 4; ++r) gates_s[m0 + q * 4 + r][nn] = acc[r];
    }
    __asm__ volatile("s_waitcnt lgkmcnt(0)" ::: "memory");

    // pointwise LSTM cell (fp32)
    float xi = gates_s[eb][ed] + bias_s[ed];
    float xf = gates_s[eb][4 + ed] + bias_s[4 + ed];
    float xg = gates_s[eb][8 + ed] + bias_s[8 + ed];
    float xo = gates_s[eb][12 + ed] + bias_s[12 + ed];
    float cn = sigf(xf) * c_state + sigf(xi) * tanh_fast(xg);
    c_state = cn;
    float hv = sigf(xo) * tanh_fast(cn);

    // pack quad's 4 f16 into 8B, one write-through store per batch row
    unsigned hw = (unsigned)__builtin_bit_cast(unsigned short, (_Float16)hv);
    unsigned o1 = __shfl_down(hw, 1);
    unsigned o2 = __shfl_down(hw, 2);
    unsigned o3 = __shfl_down(hw, 3);
    if (ed == 0) {
      unsigned lo = hw | (o1 << 16), hi = o2 | (o3 << 16);
      unsigned long long u = ((unsigned long long)hi << 32) | lo;
      __hip_atomic_store((unsigned long long*)(hn + eb * HID + dim_base), u,
                         __ATOMIC_RELAXED, __HIP_MEMORY_SCOPE_AGENT);
    }

    // ---- barrier: store-only arrival + all-thread direct poll (round-4 proven) ----
    __syncthreads();  // per-wave vmcnt(0) drain: h stores globally visible
    if (tid == 0)
      __hip_atomic_store(flags + wg, (unsigned)(t + 2), __ATOMIC_RELAXED,
                         __HIP_MEMORY_SCOPE_AGENT);

    int tn = t + 1 < TSEQ ? t + 1 : t;
    accx = xpart(tn);  // hides under flag propagation

    {
      const unsigned T = (unsigned)(t + 2);
      int ok;
      do {
        unsigned v = __hip_atomic_load(flags + tid, __ATOMIC_RELAXED,
                                       __HIP_MEMORY_SCOPE_AGENT);
        ok = (v >= T);
        if (!ok) __builtin_amdgcn_s_sleep(1);
      } while (!__syncthreads_and(ok));
    }
    __builtin_amdgcn_fence(__ATOMIC_ACQUIRE, "workgroup");  // compiler ordering only
    if (do_fence) __builtin_amdgcn_fence(__ATOMIC_ACQUIRE, "agent");  // tier B only
  }

  // ---- classifier epilogue, spread over all 256 WGs ----
  {
    const _Float16* hf = hb + (size_t)(nbuf == 2 ? 0 : TSEQ) * HSTRIDE;
    int b = wg & 63;
    int ob = (wg >> 6) << 5;
    int o = ob + (tid >> 3);
    int ks = tid & 7;
    const _Float16* hr = hf + b * HID;
    const float* wr = W_clf + (size_t)o * HID;
    float s = 0.f;
    for (int k = ks; k < HID; k += 8) s += (float)hr[k] * wr[k];
    s += __shfl_down(s, 4, 8);
    s += __shfl_down(s, 2, 8);
    s += __shfl_down(s, 1, 8);
    if (ks == 0) out[b * NOUT + o] = s + b_clf[o];
  }
}

extern "C" void kernel_launch(void* const* d_in, const int* in_sizes, int n_in,
                              void* d_out, int out_size, void* d_ws, size_t ws_size,
                              hipStream_t stream) {
  const float* x = (const float*)d_in[0];
  const float* W_ih = (const float*)d_in[1];
  const float* W_hh = (const float*)d_in[2];
  const float* b_ih = (const float*)d_in[3];
  const float* b_hh = (const float*)d_in[4];
  const float* W_clf = (const float*)d_in[5];
  const float* b_clf = (const float*)d_in[6];
  float* out = (float*)d_out;

  // capacity tiers (deterministic per deployment)
  size_t hb_off_xh = (size_t)FLAGS_BYTES + XH_BYTES;
  int use_xh = (ws_size >= hb_off_xh + 2ull * HSTRIDE * 2) ? 1 : 0;
  size_t hb_off = use_xh ? hb_off_xh : FLAGS_BYTES;
  int nbuf = (ws_size >= hb_off + 513ull * HSTRIDE * 2) ? 513 : 2;
  int do_fence = (nbuf == 2) ? 1 : 0;

  // zero flags + h slot 0 (ws is 0xAA-poisoned each call)
  hipMemsetAsync(d_ws, 0, FLAGS_BYTES, stream);
  hipMemsetAsync((char*)d_ws + hb_off, 0, HSTRIDE * 2, stream);

  void* args[] = {(void*)&x,    (void*)&W_ih,  (void*)&W_hh,  (void*)&b_ih,
                  (void*)&b_hh, (void*)&W_clf, (void*)&b_clf, (void*)&out,
                  (void*)&d_ws, (void*)&nbuf,  (void*)&use_xh, (void*)&do_fence};
  hipLaunchCooperativeKernel((const void*)lstm_persist, dim3(NWG), dim3(NTHR),
                             args, 0, stream);
}

// Round 8
// 2342.762 us; speedup vs baseline: 5.6194x; 1.5708x over previous
//
#include <hip/hip_runtime.h>

#define TSEQ 512
#define BATCH 64
#define INS 512
#define HID 1024
#define NOUT 128
#define NWG 256
#define NTHR 256
#define SLOT_HALFS 65536   // 64 x 1024 halfs = 128 KB rotating slot
#define BG_HALFS 32768     // 32 x 1024 halfs per batch-group block
#define FLAGS_BYTES 32768
#define XH_OFF ((size_t)32768)
#define XH_HALFS (2ull * TSEQ * 16384)            // 16.78M halfs (33.5 MB)
#define WIHB_OFF (XH_OFF + XH_HALFS * 2)          // 33,587,200
#define WIHB_HALFS (128ull * 16384)               // 4.19 MB
#define WHHB_OFF (WIHB_OFF + WIHB_HALFS * 2)      // 37,781,504
#define WHHB_HALFS (128ull * 32768)               // 8.39 MB
#define HB_OFF_PRE (WHHB_OFF + WHHB_HALFS * 2)    // 46,170,112

typedef _Float16 half8 __attribute__((ext_vector_type(8)));
typedef float f32x4 __attribute__((ext_vector_type(4)));

__device__ __forceinline__ float sigf(float v) {
  return __builtin_amdgcn_rcpf(1.0f + __expf(-v));
}
__device__ __forceinline__ float tanh_fast(float v) {
  float e = __expf(2.0f * fabsf(v));
  float t = 1.0f - 2.0f * __builtin_amdgcn_rcpf(e + 1.0f);
  return copysignf(t, v);
}
__device__ __forceinline__ half8 cvt8(const float* p) {
  float4 lo = *(const float4*)p, hi = *(const float4*)(p + 4);
  return half8{(_Float16)lo.x, (_Float16)lo.y, (_Float16)lo.z, (_Float16)lo.w,
               (_Float16)hi.x, (_Float16)hi.y, (_Float16)hi.z, (_Float16)hi.w};
}
// async global->LDS, 16B/lane: LDS dst = uniform base + lane*16 (m97/m104 pattern)
__device__ __forceinline__ void gload_lds16(const void* g, void* l) {
  __builtin_amdgcn_global_load_lds(
      (const __attribute__((address_space(1))) unsigned int*)g,
      (__attribute__((address_space(3))) unsigned int*)l, 16, 0, 0);
}

__global__ __launch_bounds__(NTHR, 1) void lstm_persist(
    const float* __restrict__ x, const float* __restrict__ W_ih,
    const float* __restrict__ W_hh, const float* __restrict__ b_ih,
    const float* __restrict__ b_hh, const float* __restrict__ W_clf,
    const float* __restrict__ b_clf, float* __restrict__ out,
    void* ws, int nbuf, int use_pre, int do_fence) {
  // 64 KB LDS total: h-stage, with the 4.6 KB f32 gate buffer aliased at base
  // (gates written only after all h ds_reads of a step complete; staging for the
  //  next step happens only after gates are consumed — sequenced by barriers).
  __shared__ __align__(16) char smem[65536];
  _Float16* hs = (_Float16*)smem;
  float* gates = (float*)smem;  // [4][32][9] f32

  const int tid = threadIdx.x;
  const int wg = blockIdx.x;
  const int bg = wg >> 7;     // batch group: batches [32*bg, 32*bg+32)
  const int cgrp = wg & 127;  // dim group: dims [8*cgrp, 8*cgrp+8), 4 gates = 32 cols
  const int wv = tid >> 6;
  const int mi = wv >> 1;     // m-tile (16 batches) of this wave
  const int ni = wv & 1;      // n-tile (16 cols) of this wave
  const int lane = tid & 63;
  const int nn = lane & 15;
  const int kq = lane >> 4;

  unsigned* flags = (unsigned*)ws;
  _Float16* xh = (_Float16*)((char*)ws + XH_OFF);
  _Float16* wihb = (_Float16*)((char*)ws + WIHB_OFF);
  _Float16* whhb = (_Float16*)((char*)ws + WHHB_OFF);
  _Float16* hb = (_Float16*)((char*)ws + (use_pre ? HB_OFF_PRE : (size_t)FLAGS_BYTES));

  __builtin_amdgcn_fence(__ATOMIC_ACQUIRE, "agent");  // one-time: drop stale lines

  // gate-col of this lane's B-fragments: c in [0,32) -> gate c>>3, dim 8*cgrp+(c&7)
  const int c_l = 16 * ni + nn;
  const int ncol = (c_l >> 3) * HID + 8 * cgrp + (c_l & 7);

  // ---- prologue: block x, W_ih, W_hh into f16 fragment layouts in ws ----
  if (use_pre) {
    const int gtid = wg * NTHR + tid;
    for (unsigned u = gtid; u < 2097152u; u += NWG * NTHR) {  // xh
      int ko = u & 63, t = (u >> 6) & (TSEQ - 1), b = u >> 15;
      half8 v = cvt8(x + ((size_t)b * TSEQ + t) * INS + ko * 8);
      size_t d = ((size_t)((b >> 5) * TSEQ + t) << 14) +
                 (size_t)(((((b >> 4) & 1) * 16 + (ko >> 2)) * 512) +
                          ((ko & 3) * 16 + (b & 15)) * 8);
      *(half8*)(xh + d) = v;
    }
    for (unsigned u = gtid; u < 262144u; u += NWG * NTHR) {  // wihb
      int le = u & 63, kc = (u >> 6) & 15, nie = (u >> 10) & 1, cge = u >> 11;
      int c = nie * 16 + (le & 15);
      int nc = (c >> 3) * HID + 8 * cge + (c & 7);
      half8 v = cvt8(W_ih + (size_t)nc * INS + kc * 32 + (le >> 4) * 8);
      *(half8*)(wihb + (((size_t)cge << 14) + (size_t)((nie * 16 + kc) * 512 + le * 8))) = v;
    }
    for (unsigned u = gtid; u < 524288u; u += NWG * NTHR) {  // whhb
      int le = u & 63, kc = (u >> 6) & 31, nie = (u >> 11) & 1, cge = u >> 12;
      int c = nie * 16 + (le & 15);
      int nc = (c >> 3) * HID + 8 * cge + (c & 7);
      half8 v = cvt8(W_hh + (size_t)nc * HID + kc * 32 + (le >> 4) * 8);
      *(half8*)(whhb + (((size_t)cge << 15) + (size_t)((nie * 32 + kc) * 512 + le * 8))) = v;
    }
    __builtin_amdgcn_fence(__ATOMIC_RELEASE, "agent");  // publish (one wbL2)
  }

  // pointwise constants
  const int dl = tid & 7, blp = tid >> 3;
  const int dgl = 8 * cgrp + dl;
  const float bI = b_ih[dgl] + b_hh[dgl];
  const float bF = b_ih[HID + dgl] + b_hh[HID + dgl];
  const float bG = b_ih[2 * HID + dgl] + b_hh[2 * HID + dgl];
  const float bO = b_ih[3 * HID + dgl] + b_hh[3 * HID + dgl];

  // ---- prolog flag barrier (tag 1, all 256 WGs) ----
  __syncthreads();
  if (tid == 0)
    __hip_atomic_store(flags + wg, 1u, __ATOMIC_RELAXED, __HIP_MEMORY_SCOPE_AGENT);
  {
    int ok;
    do {
      unsigned v = __hip_atomic_load(flags + tid, __ATOMIC_RELAXED,
                                     __HIP_MEMORY_SCOPE_AGENT);
      ok = (v >= 1u);
      if (!ok) __builtin_amdgcn_s_sleep(1);
    } while (!__syncthreads_and(ok));
  }
  __builtin_amdgcn_fence(__ATOMIC_ACQUIRE, "workgroup");

  // x-projection (static inputs; runs in the flag->poll shadow)
  auto xpart = [&](int t) -> f32x4 {
    f32x4 a0 = {0.f, 0.f, 0.f, 0.f}, a1 = {0.f, 0.f, 0.f, 0.f};
    if (use_pre) {
      const _Float16* xb = xh + ((size_t)(bg * TSEQ + t) << 14) + mi * 16 * 512 + lane * 8;
      const _Float16* wb = wihb + ((size_t)cgrp << 14) + ni * 16 * 512 + lane * 8;
#pragma unroll
      for (int kc = 0; kc < 16; kc += 2) {
        half8 A0 = *(const half8*)(xb + kc * 512);
        half8 B0 = *(const half8*)(wb + kc * 512);
        half8 A1 = *(const half8*)(xb + (kc + 1) * 512);
        half8 B1 = *(const half8*)(wb + (kc + 1) * 512);
        a0 = __builtin_amdgcn_mfma_f32_16x16x32_f16(A0, B0, a0, 0, 0, 0);
        a1 = __builtin_amdgcn_mfma_f32_16x16x32_f16(A1, B1, a1, 0, 0, 0);
      }
    } else {
      const float* xr = x + ((size_t)(32 * bg + 16 * mi + nn) * TSEQ + t) * INS + kq * 8;
      const float* wr = W_ih + (size_t)ncol * INS + kq * 8;
#pragma unroll
      for (int kc = 0; kc < 16; kc += 2) {
        half8 A0 = cvt8(xr + kc * 32), B0 = cvt8(wr + kc * 32);
        half8 A1 = cvt8(xr + (kc + 1) * 32), B1 = cvt8(wr + (kc + 1) * 32);
        a0 = __builtin_amdgcn_mfma_f32_16x16x32_f16(A0, B0, a0, 0, 0, 0);
        a1 = __builtin_amdgcn_mfma_f32_16x16x32_f16(A1, B1, a1, 0, 0, 0);
      }
    }
    return a0 + a1;
  };

  f32x4 accx = xpart(0);
  float c_state = 0.f;
  int sr = 0;  // slot holding h_t

  for (int t = 0; t < TSEQ; ++t) {
    int sw = sr + 1; if (sw == nbuf) sw = 0;

    // ---- stage h_t bg-block (64 KB) into LDS: 16x global_load_lds per wave ----
    {
      const _Float16* hsrc = hb + (size_t)sr * SLOT_HALFS + (size_t)bg * BG_HALFS +
                             wv * 8192 + lane * 8;
      char* ldst = smem + (size_t)wv * 16384;
#pragma unroll
      for (int i = 0; i < 16; ++i)
        gload_lds16(hsrc + i * 512, ldst + i * 1024);
    }
    __syncthreads();  // drains vmcnt: staged data + prior stores

    // ---- K=1024 MFMAs: A from LDS frags, B from L2-resident blocked whhb ----
    f32x4 a0 = accx, a1 = {0.f, 0.f, 0.f, 0.f};
    {
      const _Float16* wc = whhb + ((size_t)cgrp << 15) + ni * 32 * 512 + lane * 8;
      const _Float16* ab = hs + mi * 32 * 512 + lane * 8;
#pragma unroll
      for (int kc = 0; kc < 32; kc += 2) {
        half8 A0 = *(const half8*)(ab + kc * 512);
        half8 B0 = *(const half8*)(wc + kc * 512);
        half8 A1 = *(const half8*)(ab + (kc + 1) * 512);
        half8 B1 = *(const half8*)(wc + (kc + 1) * 512);
        a0 = __builtin_amdgcn_mfma_f32_16x16x32_f16(A0, B0, a0, 0, 0, 0);
        a1 = __builtin_amdgcn_mfma_f32_16x16x32_f16(A1, B1, a1, 0, 0, 0);
      }
    }
    f32x4 acc = a0 + a1;
    __syncthreads();  // all hs reads done before gates alias is written

    // D-scatter: row = mi*16 + q*4 + r (batch-local), col c = ni*16 + nn
    {
      int gx = c_l >> 3, dx = c_l & 7, bx = mi * 16 + kq * 4;
#pragma unroll
      for (int r = 0; r < 4; ++r) gates[(gx * 32 + bx + r) * 9 + dx] = acc[r];
    }
    __syncthreads();

    // ---- pointwise LSTM cell: thread = (batch-local blp, dim-local dl) ----
    float xi = gates[(0 * 32 + blp) * 9 + dl] + bI;
    float xf = gates[(1 * 32 + blp) * 9 + dl] + bF;
    float xg = gates[(2 * 32 + blp) * 9 + dl] + bG;
    float xo = gates[(3 * 32 + blp) * 9 + dl] + bO;
    float cn = sigf(xf) * c_state + sigf(xi) * tanh_fast(xg);
    c_state = cn;
    float hv = sigf(xo) * tanh_fast(cn);

    // pack 4 dims -> 8B agent-scope store into fragment-blocked slot
    {
      unsigned hw = (unsigned)__builtin_bit_cast(unsigned short, (_Float16)hv);
      unsigned o1 = __shfl_down(hw, 1), o2 = __shfl_down(hw, 2), o3 = __shfl_down(hw, 3);
      if ((dl & 3) == 0) {
        unsigned lo = hw | (o1 << 16), hi2 = o2 | (o3 << 16);
        unsigned long long u = ((unsigned long long)hi2 << 32) | lo;
        _Float16* hd = hb + (size_t)sw * SLOT_HALFS + (size_t)bg * BG_HALFS;
        size_t idx = (size_t)(((blp >> 4) * 32 + (cgrp >> 2)) * 512) +
                     (size_t)(((cgrp & 3) * 16 + (blp & 15)) * 8 + (dl & 4));
        __hip_atomic_store((unsigned long long*)(hd + idx), u, __ATOMIC_RELAXED,
                           __HIP_MEMORY_SCOPE_AGENT);
      }
    }

    // ---- subgroup barrier: store-only arrival + 128-flag direct poll ----
    __syncthreads();  // vmcnt drain: h stores acked at coherence point
    if (tid == 0)
      __hip_atomic_store(flags + wg, (unsigned)(t + 2), __ATOMIC_RELAXED,
                         __HIP_MEMORY_SCOPE_AGENT);

    int tn = t + 1 < TSEQ ? t + 1 : t;
    accx = xpart(tn);  // static-input work hides under flag propagation

    {
      const unsigned T = (unsigned)(t + 2);
      int ok;
      do {
        int okl = 1;
        if (tid < 128) {
          unsigned v = __hip_atomic_load(flags + bg * 128 + tid, __ATOMIC_RELAXED,
                                         __HIP_MEMORY_SCOPE_AGENT);
          okl = (v >= T);
        }
        ok = okl;
        if (!ok) __builtin_amdgcn_s_sleep(1);
      } while (!__syncthreads_and(ok));
    }
    __builtin_amdgcn_fence(__ATOMIC_ACQUIRE, "workgroup");
    if (do_fence) __builtin_amdgcn_fence(__ATOMIC_ACQUIRE, "agent");  // 2-slot tier
    sr = sw;
  }

  // ---- classifier: WG -> batch 32*bg + (cgrp>>2), outs (cgrp&3)*32 + tid>>3 ----
  {
    const _Float16* hf = hb + (size_t)sr * SLOT_HALFS + (size_t)bg * BG_HALFS;
    int bl = cgrp >> 2;
    int b = 32 * bg + bl;
    int o = (cgrp & 3) * 32 + (tid >> 3);
    int ks = tid & 7;
    int mif = bl >> 4, ml = bl & 15;
    const float* wr = W_clf + (size_t)o * HID;
    float s = 0.f;
    for (int i = 0; i < 128; ++i) {
      size_t idx = (size_t)((mif * 32 + (i >> 2)) * 512) +
                   (size_t)(((i & 3) * 16 + ml) * 8 + ks);
      s += (float)hf[idx] * wr[8 * i + ks];
    }
    s += __shfl_down(s, 4, 8);
    s += __shfl_down(s, 2, 8);
    s += __shfl_down(s, 1, 8);
    if (ks == 0) out[b * NOUT + o] = s + b_clf[o];
  }
}

extern "C" void kernel_launch(void* const* d_in, const int* in_sizes, int n_in,
                              void* d_out, int out_size, void* d_ws, size_t ws_size,
                              hipStream_t stream) {
  const float* x = (const float*)d_in[0];
  const float* W_ih = (const float*)d_in[1];
  const float* W_hh = (const float*)d_in[2];
  const float* b_ih = (const float*)d_in[3];
  const float* b_hh = (const float*)d_in[4];
  const float* W_clf = (const float*)d_in[5];
  const float* b_clf = (const float*)d_in[6];
  float* out = (float*)d_out;

  int use_pre = (ws_size >= HB_OFF_PRE + 2ull * SLOT_HALFS * 2) ? 1 : 0;
  size_t hb_off = use_pre ? HB_OFF_PRE : (size_t)FLAGS_BYTES;
  int nbuf = (ws_size >= hb_off + 129ull * SLOT_HALFS * 2) ? 129 : 2;
  int do_fence = (nbuf == 2) ? 1 : 0;

  hipMemsetAsync(d_ws, 0, FLAGS_BYTES, stream);                       // flags
  hipMemsetAsync((char*)d_ws + hb_off, 0, SLOT_HALFS * 2, stream);    // h slot 0

  void* args[] = {(void*)&x,    (void*)&W_ih,  (void*)&W_hh,   (void*)&b_ih,
                  (void*)&b_hh, (void*)&W_clf, (void*)&b_clf,  (void*)&out,
                  (void*)&d_ws, (void*)&nbuf,  (void*)&use_pre, (void*)&do_fence};
  hipLaunchCooperativeKernel((const void*)lstm_persist, dim3(NWG), dim3(NTHR),
                             args, 0, stream);
}